// Round 18
// baseline (259.472 us; speedup 1.0000x reference)
//
#include <hip/hip_runtime.h>
#include <cstdint>
#include <cstddef>

#define B_ 8
#define T_ 4096
#define C_ 256
#define NC_ 256
#define L_ (T_ / NC_)   // 16 steps per chunk
#define M_ (B_ * T_)    // 32768 rows

typedef float f32x4 __attribute__((ext_vector_type(4)));
typedef short bf16x8 __attribute__((ext_vector_type(8)));

__device__ __forceinline__ unsigned short f2b(float f) {
    unsigned int u = __float_as_uint(f);
    u += 0x7fffu + ((u >> 16) & 1u);   // round-to-nearest-even
    return (unsigned short)(u >> 16);
}
__device__ __forceinline__ float b2f(unsigned short h) {
    return __uint_as_float(((unsigned int)h) << 16);
}

// ---------------- f32->bf16 convert: WEIGHTS ONLY ------------------------------
__global__ __launch_bounds__(256) void cvt_w(const float* __restrict__ Wk,
                                             const float* __restrict__ Wv,
                                             const float* __restrict__ Wr,
                                             const float* __restrict__ Wo,
                                             unsigned short* __restrict__ wb) {
    const int r = blockIdx.x;              // 0..127
    const int mat = r >> 5;                // 0..3
    const float* src = (mat == 0) ? Wk : (mat == 1) ? Wv : (mat == 2) ? Wr : Wo;
    unsigned short* dst = wb + (size_t)mat * 65536;
    const size_t i = (size_t)(r & 31) * 2048 + (size_t)threadIdx.x * 8;
    float4 a = *(const float4*)(src + i);
    float4 b = *(const float4*)(src + i + 4);
    bf16x8 o;
    o[0] = (short)f2b(a.x); o[1] = (short)f2b(a.y);
    o[2] = (short)f2b(a.z); o[3] = (short)f2b(a.w);
    o[4] = (short)f2b(b.x); o[5] = (short)f2b(b.y);
    o[6] = (short)f2b(b.z); o[7] = (short)f2b(b.w);
    *(bf16x8*)(dst + i) = o;
}

// ---------------- QKV GEMM v13: BARRIER-FREE (W fragments direct from global) -
// O[m,n] = sum_k A[m,k]*W[n,k], A = bf16(x) in-register. Grid (M/64, 2) = 1024
// blocks, 2 strips x 3 mats per block. NO wlds, NO __syncthreads: the MFMA
// B-fragment is loaded directly from global W (identical values/lanes as the
// old LDS path); cross-wave W sharing happens via L1 (each phase's W strip is
// exactly 32 KB = one L1). Removes all 24 vmcnt(0) barrier drains per block
// (the measured latency cost hipcc can't pipeline across s_barrier). LDS =
// per-wave stage only (17.4 KB). k/v/sr stored transposed bf16 (R16); fused
// pass1 scan at mat==1. Worst case = L2-BW ceiling (~23 us) < old 43 us.
__global__ __launch_bounds__(256) void gemm_qkv(const float* __restrict__ x,
                                                const unsigned short* __restrict__ w0,
                                                const unsigned short* __restrict__ w1,
                                                const unsigned short* __restrict__ w2,
                                                const float* __restrict__ decay,
                                                unsigned short* __restrict__ kb,
                                                unsigned short* __restrict__ vb,
                                                unsigned short* __restrict__ b2,
                                                float* __restrict__ sp,
                                                float* __restrict__ sq,
                                                float* __restrict__ so) {
    __shared__ float stage[4][16 * 68];         // 17408 B, per-wave regions only
    const int tid = threadIdx.x;
    const int wave = tid >> 6, lane = tid & 63;
    const int quad = lane >> 4, l16 = lane & 15;
    const int m0 = blockIdx.x * 64 + wave * 16;
    const int s0 = blockIdx.y * 2;              // strips s0, s0+1
    float* myst = stage[wave];

    // A fragments from f32 x, converted in-register (bit-identical to cvt path)
    bf16x8 af[8];
    {
        const float* Ar = x + (size_t)(m0 + l16) * C_ + quad * 8;
#pragma unroll
        for (int kc = 0; kc < 8; ++kc) {
            float4 a = *(const float4*)(Ar + kc * 32);
            float4 b = *(const float4*)(Ar + kc * 32 + 4);
            bf16x8 o;
            o[0] = (short)f2b(a.x); o[1] = (short)f2b(a.y);
            o[2] = (short)f2b(a.z); o[3] = (short)f2b(a.w);
            o[4] = (short)f2b(b.x); o[5] = (short)f2b(b.y);
            o[6] = (short)f2b(b.z); o[7] = (short)f2b(b.w);
            af[kc] = o;
        }
    }

    const int bb = m0 / T_;
    const int chunk = (m0 % T_) / L_;
    const size_t colbase = ((size_t)bb * NC_ + chunk) * C_;   // + ch, then *16

    float kreg[16], vreg[16];            // chunk-local k/v (bf16-rounded)

    for (int sl = 0; sl < 2; ++sl) {
        const int n0 = (s0 + sl) * 64;
        for (int mat = 0; mat < 3; ++mat) {
            const unsigned short* W = (mat == 0) ? w0 : (mat == 1) ? w1 : w2;

            f32x4 acc[4];
#pragma unroll
            for (int nt = 0; nt < 4; ++nt) acc[nt] = (f32x4){0.f, 0.f, 0.f, 0.f};
#pragma unroll
            for (int nt = 0; nt < 4; ++nt) {
                const unsigned short* wr = W + (size_t)(n0 + nt * 16 + l16) * C_ + quad * 8;
                bf16x8 wf[8];
#pragma unroll
                for (int kc = 0; kc < 8; ++kc) wf[kc] = *(const bf16x8*)(wr + kc * 32);
#pragma unroll
                for (int kc = 0; kc < 8; ++kc)
                    acc[nt] = __builtin_amdgcn_mfma_f32_16x16x32_bf16(af[kc], wf[kc], acc[nt], 0, 0, 0);
            }

            // per-wave stage (no barriers; same-wave LDS ops are ordered)
#pragma unroll
            for (int nt = 0; nt < 4; ++nt)
#pragma unroll
                for (int i = 0; i < 4; ++i)
                    myst[(quad * 4 + i) * 68 + nt * 16 + l16] = acc[nt][i];

            const int ch = n0 + lane;
            unsigned short* dst = (mat == 0) ? kb : (mat == 1) ? vb : b2;
            unsigned short* cd = dst + (colbase + ch) * 16;
            if (mat == 0) {
                bf16x8 p0, p1;
#pragma unroll
                for (int j = 0; j < 8; ++j) p0[j] = (short)f2b(myst[j * 68 + lane]);
#pragma unroll
                for (int j = 0; j < 8; ++j) p1[j] = (short)f2b(myst[(8 + j) * 68 + lane]);
                *(bf16x8*)(cd) = p0;
                *(bf16x8*)(cd + 8) = p1;
#pragma unroll
                for (int j = 0; j < 8; ++j) {
                    kreg[j] = b2f((unsigned short)p0[j]);
                    kreg[8 + j] = b2f((unsigned short)p1[j]);
                }
            } else if (mat == 1) {
                bf16x8 p0, p1;
#pragma unroll
                for (int j = 0; j < 8; ++j) p0[j] = (short)f2b(myst[j * 68 + lane]);
#pragma unroll
                for (int j = 0; j < 8; ++j) p1[j] = (short)f2b(myst[(8 + j) * 68 + lane]);
                *(bf16x8*)(cd) = p0;
                *(bf16x8*)(cd + 8) = p1;
#pragma unroll
                for (int j = 0; j < 8; ++j) {
                    vreg[j] = b2f((unsigned short)p0[j]);
                    vreg[8 + j] = b2f((unsigned short)p1[j]);
                }
                // fused pass1 scan (bit-identical values)
                const float w = decay[ch] * (1.0f / T_);
                float p = 0.f, q = 0.f, o = -1e38f;
#pragma unroll
                for (int j = 0; j < L_; ++j) {
                    float wo = w + o;
                    float no = fmaxf(wo, kreg[j]);
                    float a2 = __expf(wo - no), b2s = __expf(kreg[j] - no);
                    p = a2 * p + b2s * vreg[j];
                    q = a2 * q + b2s;
                    o = no;
                }
                const size_t idx = colbase + ch;
                sp[idx] = p; sq[idx] = q; so[idx] = o;
            } else {
                bf16x8 p0, p1;
#pragma unroll
                for (int j = 0; j < 8; ++j)
                    p0[j] = (short)f2b(1.f / (1.f + __expf(-myst[j * 68 + lane])));
#pragma unroll
                for (int j = 0; j < 8; ++j)
                    p1[j] = (short)f2b(1.f / (1.f + __expf(-myst[(8 + j) * 68 + lane])));
                *(bf16x8*)(cd) = p0;
                *(bf16x8*)(cd + 8) = p1;
            }
        }
    }
}

// ---------------- output GEMM v9: BARRIER-FREE, 1 strip/block -----------------
// Grid (M/64, 4) = 2048 blocks. W fragments direct from global (L1-shared
// across the block's 4 waves); zb read per-strip (bf16, L3-hot). Zero
// __syncthreads; staged full-line stores via per-wave LDS region (R4 lesson).
__global__ __launch_bounds__(256) void gemm_out(const unsigned short* __restrict__ A,
                                                const unsigned short* __restrict__ w0,
                                                float* __restrict__ f0) {
    __shared__ float stage[4][16 * 68];         // 17408 B
    const int tid = threadIdx.x;
    const int wave = tid >> 6, lane = tid & 63;
    const int quad = lane >> 4, l16 = lane & 15;
    const int m0 = blockIdx.x * 64 + wave * 16;
    const int n0 = blockIdx.y * 64;
    float* myst = stage[wave];

    bf16x8 af[8];
    {
        const unsigned short* Ar = A + (size_t)(m0 + l16) * C_ + quad * 8;
#pragma unroll
        for (int kc = 0; kc < 8; ++kc) af[kc] = *(const bf16x8*)(Ar + kc * 32);
    }

    f32x4 acc[4];
#pragma unroll
    for (int nt = 0; nt < 4; ++nt) acc[nt] = (f32x4){0.f, 0.f, 0.f, 0.f};
#pragma unroll
    for (int nt = 0; nt < 4; ++nt) {
        const unsigned short* wr = w0 + (size_t)(n0 + nt * 16 + l16) * C_ + quad * 8;
        bf16x8 wf[8];
#pragma unroll
        for (int kc = 0; kc < 8; ++kc) wf[kc] = *(const bf16x8*)(wr + kc * 32);
#pragma unroll
        for (int kc = 0; kc < 8; ++kc)
            acc[nt] = __builtin_amdgcn_mfma_f32_16x16x32_bf16(af[kc], wf[kc], acc[nt], 0, 0, 0);
    }

    // per-wave stage -> full-line stores (no barriers)
#pragma unroll
    for (int nt = 0; nt < 4; ++nt)
#pragma unroll
        for (int i = 0; i < 4; ++i)
            myst[(quad * 4 + i) * 68 + nt * 16 + l16] = acc[nt][i];
#pragma unroll
    for (int rr = 0; rr < 4; ++rr) {
        const int row = rr * 4 + quad;
        float4 t4 = *(const float4*)&myst[row * 68 + l16 * 4];
        *(float4*)(f0 + (size_t)(m0 + row) * C_ + n0 + l16 * 4) = t4;
    }
}

// ---------------- WKV combine: PARALLEL segmented scan over chunks ------------
__global__ __launch_bounds__(256) void wkv_combine_par(const float* __restrict__ decay,
                                                       float* __restrict__ sp,
                                                       float* __restrict__ sq,
                                                       float* __restrict__ so) {
    __shared__ float tp[16][17], tq[16][17], to[16][17];
    const int tid = threadIdx.x;
    const int cgi = tid >> 4;
    const int cl = tid & 15;
    const int b = blockIdx.x;
    const int c = blockIdx.y * 16 + cl;
    const float wL = decay[c] * (1.0f / T_) * (float)L_;
    const float wL16 = wL * 16.0f;
    const size_t base = ((size_t)b * NC_ + (size_t)cgi * 16) * C_ + c;

    float p = 0.f, q = 0.f, o = -1e38f;
#pragma unroll 4
    for (int j = 0; j < 16; ++j) {
        size_t idx = base + (size_t)j * C_;
        float lp = sp[idx], lq = sq[idx], lo = so[idx];
        float ow = o + wL;
        float no = fmaxf(ow, lo);
        float ea = __expf(ow - no), eb = __expf(lo - no);
        p = ea * p + eb * lp;
        q = ea * q + eb * lq;
        o = no;
    }
    tp[cgi][cl] = p; tq[cgi][cl] = q; to[cgi][cl] = o;

    float ip = p, iq = q, io = o;
#pragma unroll
    for (int off = 1; off < 16; off <<= 1) {
        __syncthreads();
        float ap = 0.f, aq = 0.f, ao = 0.f;
        const bool doit = (cgi >= off);
        if (doit) { ap = tp[cgi - off][cl]; aq = tq[cgi - off][cl]; ao = to[cgi - off][cl]; }
        __syncthreads();
        if (doit) {
            float ow = ao + (float)off * wL16;
            float no = fmaxf(ow, io);
            float ea = __expf(ow - no), eb = __expf(io - no);
            ip = ea * ap + eb * ip;
            iq = ea * aq + eb * iq;
            io = no;
            tp[cgi][cl] = ip; tq[cgi][cl] = iq; to[cgi][cl] = io;
        }
    }
    __syncthreads();

    float ep, eq, eo;
    if (cgi == 0) { ep = 0.f; eq = 0.f; eo = -1e38f; }
    else          { ep = tp[cgi - 1][cl]; eq = tq[cgi - 1][cl]; eo = to[cgi - 1][cl]; }

    for (int j = 0; j < 16; ++j) {
        size_t idx = base + (size_t)j * C_;
        float lp = sp[idx], lq = sq[idx], lo = so[idx];
        sp[idx] = ep; sq[idx] = eq; so[idx] = eo;
        float ow = eo + wL;
        float no = fmaxf(ow, lo);
        float ea = __expf(ow - no), eb = __expf(lo - no);
        ep = ea * ep + eb * lp;
        eq = ea * eq + eb * lq;
        eo = no;
    }
}

// ---------------- WKV pass 2 + LN + gate: vector loads, rcp-based divide ------
__global__ __launch_bounds__(256, 8) void wkv_pass2_ln(const unsigned short* __restrict__ k,
                                                       const unsigned short* __restrict__ v,
                                                       const unsigned short* __restrict__ sr,
                                                       const float* __restrict__ decay,
                                                       const float* __restrict__ first,
                                                       const float* __restrict__ lw,
                                                       const float* __restrict__ lb,
                                                       const float* __restrict__ sp,
                                                       const float* __restrict__ sq,
                                                       const float* __restrict__ so,
                                                       unsigned short* __restrict__ z) {
    __shared__ float tile[16][264];
    __shared__ float mu_s[16], rs_s[16];
    const int c = threadIdx.x, chunk = blockIdx.x, b = blockIdx.y;
    const int wave = c >> 6, lane = c & 63;
    const float w = decay[c] * (1.0f / T_);
    const float u = first[c] * (1.0f / T_);
    const float gw = lw[c], gb = lb[c];
    size_t sidx = ((size_t)b * NC_ + chunk) * C_ + c;
    float p = sp[sidx], q = sq[sidx], o = so[sidx];
    size_t base = ((size_t)b * T_ + (size_t)chunk * L_) * C_ + c;

    // transposed column tile: 2x bf16x8 per operand (32B/lane, wave = 2KB)
    const unsigned short* kp = k + sidx * 16;
    const unsigned short* vp = v + sidx * 16;
    bf16x8 k0 = *(const bf16x8*)(kp), k1 = *(const bf16x8*)(kp + 8);
    bf16x8 v0 = *(const bf16x8*)(vp), v1 = *(const bf16x8*)(vp + 8);

#pragma unroll
    for (int j = 0; j < L_; ++j) {
        float kj = b2f((unsigned short)((j < 8) ? k0[j] : k1[j - 8]));
        float vj = b2f((unsigned short)((j < 8) ? v0[j] : v1[j - 8]));
        float uk = u + kj;
        float no = fmaxf(o, uk);
        float a = __expf(o - no), bb = __expf(uk - no);
        tile[j][c] = (a * p + bb * vj) * __builtin_amdgcn_rcpf(a * q + bb);
        float wo = w + o;
        float no2 = fmaxf(wo, kj);
        float a2 = __expf(wo - no2), b2 = __expf(kj - no2);
        p = a2 * p + b2 * vj;
        q = a2 * q + b2;
        o = no2;
    }
    __syncthreads();
#pragma unroll
    for (int r = 0; r < 4; ++r) {
        const int j = wave * 4 + r;
        float4 t4 = *(const float4*)&tile[j][lane * 4];
        float s = t4.x + t4.y + t4.z + t4.w;
        float ss = t4.x * t4.x + t4.y * t4.y + t4.z * t4.z + t4.w * t4.w;
#pragma unroll
        for (int m = 1; m < 64; m <<= 1) {
            s += __shfl_xor(s, m, 64);
            ss += __shfl_xor(ss, m, 64);
        }
        if (lane == 0) {
            float mu = s * (1.f / C_);
            mu_s[j] = mu;
            rs_s[j] = rsqrtf(ss * (1.f / C_) - mu * mu + 1e-5f);
        }
    }
    __syncthreads();
    const unsigned short* srp = sr + sidx * 16;
    bf16x8 s0 = *(const bf16x8*)(srp), s1 = *(const bf16x8*)(srp + 8);
#pragma unroll
    for (int j = 0; j < L_; ++j) {
        float zz = (tile[j][c] - mu_s[j]) * rs_s[j] * gw + gb;
        zz *= b2f((unsigned short)((j < 8) ? s0[j] : s1[j - 8]));
        z[base + (size_t)j * C_] = f2b(zz);
    }
}

extern "C" void kernel_launch(void* const* d_in, const int* in_sizes, int n_in,
                              void* d_out, int out_size, void* d_ws, size_t ws_size,
                              hipStream_t stream) {
    const float* x     = (const float*)d_in[0];
    const float* Wk    = (const float*)d_in[1];
    const float* Wv    = (const float*)d_in[2];
    const float* Wr    = (const float*)d_in[3];
    const float* Wo    = (const float*)d_in[4];
    const float* decay = (const float*)d_in[5];
    const float* first = (const float*)d_in[6];
    const float* lnw   = (const float*)d_in[7];
    const float* lnb   = (const float*)d_in[8];
    float* out = (float*)d_out;

    char* ws = (char*)d_ws;
    const size_t NE = (size_t)M_ * C_;              // 8388608
    unsigned short* wb  = (unsigned short*)ws; ws += 4 * 65536 * 2;  // wk|wv|wr|wo
    unsigned short* kbuf = (unsigned short*)ws; ws += NE * 2;        // bf16 k (transposed)
    unsigned short* vbuf = (unsigned short*)ws; ws += NE * 2;        // bf16 v (transposed)
    unsigned short* srb = (unsigned short*)ws; ws += NE * 2;         // bf16 sr (transposed)
    unsigned short* zb  = (unsigned short*)ws; ws += NE * 2;         // bf16 z (row-major)
    const size_t SE = (size_t)B_ * NC_ * C_;        // 524288
    float* sp = (float*)ws; ws += SE * 4;
    float* sq = (float*)ws; ws += SE * 4;
    float* so = (float*)ws; ws += SE * 4;
    unsigned short* wkb = wb;
    unsigned short* wvb = wb + 65536;
    unsigned short* wrb = wb + 2 * 65536;
    unsigned short* wob = wb + 3 * 65536;

    cvt_w<<<128, 256, 0, stream>>>(Wk, Wv, Wr, Wo, wb);

    // QKV + fused pass1: (512 row-blocks x 2 strip-pairs) = 1024 blocks,
    // barrier-free; W fragments direct from global (L1-shared).
    gemm_qkv<<<dim3(M_ / 64, 2), 256, 0, stream>>>(x, wkb, wvb, wrb, decay,
                                                   kbuf, vbuf, srb, sp, sq, so);

    wkv_combine_par<<<dim3(B_, C_ / 16), 256, 0, stream>>>(decay, sp, sq, so);
    wkv_pass2_ln<<<dim3(NC_, B_), 256, 0, stream>>>(kbuf, vbuf, srb, decay, first,
                                                    lnw, lnb, sp, sq, so, zb);

    // Output GEMM: (512 row-blocks x 4 strips) = 2048 blocks, barrier-free.
    gemm_out<<<dim3(M_ / 64, 4), 256, 0, stream>>>(zb, wob, out);
}

// Round 19
// 157.707 us; speedup vs baseline: 1.6453x; 1.6453x over previous
//
#include <hip/hip_runtime.h>
#include <cstdint>
#include <cstddef>

#define B_ 8
#define T_ 4096
#define C_ 256
#define NC_ 256
#define L_ (T_ / NC_)   // 16 steps per chunk
#define M_ (B_ * T_)    // 32768 rows

typedef float f32x4 __attribute__((ext_vector_type(4)));
typedef short bf16x8 __attribute__((ext_vector_type(8)));

__device__ __forceinline__ unsigned short f2b(float f) {
    unsigned int u = __float_as_uint(f);
    u += 0x7fffu + ((u >> 16) & 1u);   // round-to-nearest-even
    return (unsigned short)(u >> 16);
}
__device__ __forceinline__ float b2f(unsigned short h) {
    return __uint_as_float(((unsigned int)h) << 16);
}

// ---------------- f32->bf16 convert: WEIGHTS ONLY (x fused into gemm_qkv) -----
__global__ __launch_bounds__(256) void cvt_w(const float* __restrict__ Wk,
                                             const float* __restrict__ Wv,
                                             const float* __restrict__ Wr,
                                             const float* __restrict__ Wo,
                                             unsigned short* __restrict__ wb) {
    const int r = blockIdx.x;              // 0..127
    const int mat = r >> 5;                // 0..3
    const float* src = (mat == 0) ? Wk : (mat == 1) ? Wv : (mat == 2) ? Wr : Wo;
    unsigned short* dst = wb + (size_t)mat * 65536;
    const size_t i = (size_t)(r & 31) * 2048 + (size_t)threadIdx.x * 8;
    float4 a = *(const float4*)(src + i);
    float4 b = *(const float4*)(src + i + 4);
    bf16x8 o;
    o[0] = (short)f2b(a.x); o[1] = (short)f2b(a.y);
    o[2] = (short)f2b(a.z); o[3] = (short)f2b(a.w);
    o[4] = (short)f2b(b.x); o[5] = (short)f2b(b.y);
    o[6] = (short)f2b(b.z); o[7] = (short)f2b(b.w);
    *(bf16x8*)(dst + i) = o;
}

// ---------------- QKV GEMM (R14 best): strip-looped, direct f32 x, fused pass1
// O[m,n] = sum_k A[m,k]*W[n,k], A = bf16(x) converted in-register (bit-identical
// to the old cvt_all path). Grid (M/64) = 512 blocks, 4 n-strips x 3 mats
// looped (12 phases) -> each x row read exactly ONCE device-wide. W staged in
// LDS (R18 lesson: direct-global B-fragments destroy coalescing, 3x slower).
// k/v stored bf16 (R13); fused pass1 scan per (strip, mat==1). Separate stage
// buffer (R11 lesson); no reg cap beyond (256,3) (R10 lesson).
__global__ __launch_bounds__(256, 3) void gemm_qkv(const float* __restrict__ x,
                                                   const unsigned short* __restrict__ w0,
                                                   const unsigned short* __restrict__ w1,
                                                   const unsigned short* __restrict__ w2,
                                                   const float* __restrict__ decay,
                                                   unsigned short* __restrict__ kb,
                                                   unsigned short* __restrict__ vb,
                                                   unsigned short* __restrict__ b2,
                                                   float* __restrict__ sp,
                                                   float* __restrict__ sq,
                                                   float* __restrict__ so) {
    __shared__ unsigned short wlds[64 * 264];   // 33792 B
    __shared__ float stage[4][16 * 68];         // 17408 B (total 51200 -> 3 blk/CU)
    const int tid = threadIdx.x;
    const int wave = tid >> 6, lane = tid & 63;
    const int quad = lane >> 4, l16 = lane & 15;
    const int m0 = blockIdx.x * 64 + wave * 16;
    float* myst = stage[wave];

    // A fragments from f32 x, converted in-register (bit-identical to cvt path)
    bf16x8 af[8];
    {
        const float* Ar = x + (size_t)(m0 + l16) * C_ + quad * 8;
#pragma unroll
        for (int kc = 0; kc < 8; ++kc) {
            float4 a = *(const float4*)(Ar + kc * 32);
            float4 b = *(const float4*)(Ar + kc * 32 + 4);
            bf16x8 o;
            o[0] = (short)f2b(a.x); o[1] = (short)f2b(a.y);
            o[2] = (short)f2b(a.z); o[3] = (short)f2b(a.w);
            o[4] = (short)f2b(b.x); o[5] = (short)f2b(b.y);
            o[6] = (short)f2b(b.z); o[7] = (short)f2b(b.w);
            af[kc] = o;
        }
    }

    const int r = tid >> 5;              // 0..7
    const int cs = (tid & 31) * 8;       // short offset, 16 B per lane

    bf16x8 tmp[8];
#pragma unroll
    for (int it = 0; it < 8; ++it)
        tmp[it] = *(const bf16x8*)(w0 + (size_t)(it * 8 + r) * C_ + cs);

    float kreg[16], vreg[16];            // chunk-local k/v (bf16-rounded)

    for (int s = 0; s < 4; ++s) {
        const int n0 = s * 64;
        for (int mat = 0; mat < 3; ++mat) {
            __syncthreads();             // prev phase's wlds reads done
#pragma unroll
            for (int it = 0; it < 8; ++it)
                *(bf16x8*)(wlds + (it * 8 + r) * 264 + cs) = tmp[it];
            __syncthreads();             // wlds visible to all waves

            if (!(s == 3 && mat == 2)) { // prefetch next phase's W tile
                const unsigned short* Wn = (mat == 0) ? w1 : (mat == 1) ? w2 : w0;
                const int nn = (mat == 2) ? n0 + 64 : n0;
#pragma unroll
                for (int it = 0; it < 8; ++it)
                    tmp[it] = *(const bf16x8*)(Wn + (size_t)(nn + it * 8 + r) * C_ + cs);
            }

            f32x4 acc[4];
#pragma unroll
            for (int nt = 0; nt < 4; ++nt) acc[nt] = (f32x4){0.f, 0.f, 0.f, 0.f};
#pragma unroll
            for (int nt = 0; nt < 4; ++nt) {
                const unsigned short* wrow = wlds + (nt * 16 + l16) * 264 + quad * 8;
#pragma unroll
                for (int kc = 0; kc < 8; ++kc) {
                    bf16x8 wf = *(const bf16x8*)(wrow + kc * 32);
                    acc[nt] = __builtin_amdgcn_mfma_f32_16x16x32_bf16(af[kc], wf, acc[nt], 0, 0, 0);
                }
            }

#pragma unroll
            for (int nt = 0; nt < 4; ++nt)
#pragma unroll
                for (int i = 0; i < 4; ++i)
                    myst[(quad * 4 + i) * 68 + nt * 16 + l16] = acc[nt][i];
#pragma unroll
            for (int rr = 0; rr < 4; ++rr) {
                const int row = rr * 4 + quad;
                float4 t4 = *(const float4*)&myst[row * 68 + l16 * 4];
                const size_t gidx = (size_t)(m0 + row) * C_ + n0 + l16 * 4;
                ushort4 s4;
                if (mat == 2) {
                    s4.x = f2b(1.f / (1.f + __expf(-t4.x)));
                    s4.y = f2b(1.f / (1.f + __expf(-t4.y)));
                    s4.z = f2b(1.f / (1.f + __expf(-t4.z)));
                    s4.w = f2b(1.f / (1.f + __expf(-t4.w)));
                    *(ushort4*)(b2 + gidx) = s4;
                } else {
                    s4.x = f2b(t4.x); s4.y = f2b(t4.y);
                    s4.z = f2b(t4.z); s4.w = f2b(t4.w);
                    unsigned short* Fb = (mat == 0) ? kb : vb;
                    *(ushort4*)(Fb + gidx) = s4;
                }
            }

            // ---- fused pass1 for this strip's 64 channels --------------------
            // myst is per-wave (wave-ordered LDS; separate buffer from wlds).
            if (mat == 0) {
#pragma unroll
                for (int j = 0; j < L_; ++j) kreg[j] = b2f(f2b(myst[j * 68 + lane]));
            } else if (mat == 1) {
#pragma unroll
                for (int j = 0; j < L_; ++j) vreg[j] = b2f(f2b(myst[j * 68 + lane]));
                const int ch = n0 + lane;
                const float w = decay[ch] * (1.0f / T_);
                float p = 0.f, q = 0.f, o = -1e38f;
#pragma unroll
                for (int j = 0; j < L_; ++j) {
                    float wo = w + o;
                    float no = fmaxf(wo, kreg[j]);
                    float a2 = __expf(wo - no), b2s = __expf(kreg[j] - no);
                    p = a2 * p + b2s * vreg[j];
                    q = a2 * q + b2s;
                    o = no;
                }
                const int bb = m0 / T_;
                const int chunk = (m0 % T_) / L_;
                const size_t idx = ((size_t)bb * NC_ + chunk) * C_ + ch;
                sp[idx] = p; sq[idx] = q; so[idx] = o;
            }
        }
    }
}

// ---------------- output GEMM (R14): 4 n-strips looped, A-frags loaded ONCE ---
__global__ __launch_bounds__(256, 3) void gemm_out(const unsigned short* __restrict__ A,
                                                   const unsigned short* __restrict__ w0,
                                                   float* __restrict__ f0) {
    __shared__ unsigned short wlds[64 * 264];   // 33792 B
    __shared__ float stage[4][16 * 68];         // 17408 B
    const int tid = threadIdx.x;
    const int wave = tid >> 6, lane = tid & 63;
    const int quad = lane >> 4, l16 = lane & 15;
    const int m0 = blockIdx.x * 64 + wave * 16;
    float* myst = stage[wave];

    bf16x8 af[8];
    {
        const unsigned short* Ar = A + (size_t)(m0 + l16) * C_ + quad * 8;
#pragma unroll
        for (int kc = 0; kc < 8; ++kc) af[kc] = *(const bf16x8*)(Ar + kc * 32);
    }

    const int r = tid >> 5;              // 0..7
    const int cs = (tid & 31) * 8;       // short offset, 16 B per lane

    bf16x8 tmp[8];
#pragma unroll
    for (int it = 0; it < 8; ++it)
        tmp[it] = *(const bf16x8*)(w0 + (size_t)(it * 8 + r) * C_ + cs);

    for (int s = 0; s < 4; ++s) {
        const int n0 = s * 64;
        __syncthreads();                 // prev strip's wlds reads done
#pragma unroll
        for (int it = 0; it < 8; ++it)
            *(bf16x8*)(wlds + (it * 8 + r) * 264 + cs) = tmp[it];
        __syncthreads();                 // wlds visible to all waves

        if (s < 3) {                     // prefetch next strip's W rows
#pragma unroll
            for (int it = 0; it < 8; ++it)
                tmp[it] = *(const bf16x8*)(w0 + (size_t)(n0 + 64 + it * 8 + r) * C_ + cs);
        }

        f32x4 acc[4];
#pragma unroll
        for (int nt = 0; nt < 4; ++nt) acc[nt] = (f32x4){0.f, 0.f, 0.f, 0.f};
#pragma unroll
        for (int nt = 0; nt < 4; ++nt) {
            const unsigned short* wrow = wlds + (nt * 16 + l16) * 264 + quad * 8;
#pragma unroll
            for (int kc = 0; kc < 8; ++kc) {
                bf16x8 wf = *(const bf16x8*)(wrow + kc * 32);
                acc[nt] = __builtin_amdgcn_mfma_f32_16x16x32_bf16(af[kc], wf, acc[nt], 0, 0, 0);
            }
        }

#pragma unroll
        for (int nt = 0; nt < 4; ++nt)
#pragma unroll
            for (int i = 0; i < 4; ++i)
                myst[(quad * 4 + i) * 68 + nt * 16 + l16] = acc[nt][i];
#pragma unroll
        for (int rr = 0; rr < 4; ++rr) {
            const int row = rr * 4 + quad;
            float4 t4 = *(const float4*)&myst[row * 68 + l16 * 4];
            *(float4*)(f0 + (size_t)(m0 + row) * C_ + n0 + l16 * 4) = t4;
        }
    }
}

// ---------------- WKV combine: PARALLEL segmented scan over chunks ------------
__global__ __launch_bounds__(256) void wkv_combine_par(const float* __restrict__ decay,
                                                       float* __restrict__ sp,
                                                       float* __restrict__ sq,
                                                       float* __restrict__ so) {
    __shared__ float tp[16][17], tq[16][17], to[16][17];
    const int tid = threadIdx.x;
    const int cgi = tid >> 4;
    const int cl = tid & 15;
    const int b = blockIdx.x;
    const int c = blockIdx.y * 16 + cl;
    const float wL = decay[c] * (1.0f / T_) * (float)L_;
    const float wL16 = wL * 16.0f;
    const size_t base = ((size_t)b * NC_ + (size_t)cgi * 16) * C_ + c;

    float p = 0.f, q = 0.f, o = -1e38f;
#pragma unroll 4
    for (int j = 0; j < 16; ++j) {
        size_t idx = base + (size_t)j * C_;
        float lp = sp[idx], lq = sq[idx], lo = so[idx];
        float ow = o + wL;
        float no = fmaxf(ow, lo);
        float ea = __expf(ow - no), eb = __expf(lo - no);
        p = ea * p + eb * lp;
        q = ea * q + eb * lq;
        o = no;
    }
    tp[cgi][cl] = p; tq[cgi][cl] = q; to[cgi][cl] = o;

    float ip = p, iq = q, io = o;
#pragma unroll
    for (int off = 1; off < 16; off <<= 1) {
        __syncthreads();
        float ap = 0.f, aq = 0.f, ao = 0.f;
        const bool doit = (cgi >= off);
        if (doit) { ap = tp[cgi - off][cl]; aq = tq[cgi - off][cl]; ao = to[cgi - off][cl]; }
        __syncthreads();
        if (doit) {
            float ow = ao + (float)off * wL16;
            float no = fmaxf(ow, io);
            float ea = __expf(ow - no), eb = __expf(io - no);
            ip = ea * ap + eb * ip;
            iq = ea * aq + eb * iq;
            io = no;
            tp[cgi][cl] = ip; tq[cgi][cl] = iq; to[cgi][cl] = io;
        }
    }
    __syncthreads();

    float ep, eq, eo;
    if (cgi == 0) { ep = 0.f; eq = 0.f; eo = -1e38f; }
    else          { ep = tp[cgi - 1][cl]; eq = tq[cgi - 1][cl]; eo = to[cgi - 1][cl]; }

    for (int j = 0; j < 16; ++j) {
        size_t idx = base + (size_t)j * C_;
        float lp = sp[idx], lq = sq[idx], lo = so[idx];
        sp[idx] = ep; sq[idx] = eq; so[idx] = eo;
        float ow = eo + wL;
        float no = fmaxf(ow, lo);
        float ea = __expf(ow - no), eb = __expf(lo - no);
        ep = ea * ep + eb * lp;
        eq = ea * eq + eb * lq;
        eo = no;
    }
}

// ---------------- WKV pass 2 + LayerNorm + gate (bf16 k/v inputs) --------------
__global__ __launch_bounds__(256, 8) void wkv_pass2_ln(const unsigned short* __restrict__ k,
                                                       const unsigned short* __restrict__ v,
                                                       const unsigned short* __restrict__ sr,
                                                       const float* __restrict__ decay,
                                                       const float* __restrict__ first,
                                                       const float* __restrict__ lw,
                                                       const float* __restrict__ lb,
                                                       const float* __restrict__ sp,
                                                       const float* __restrict__ sq,
                                                       const float* __restrict__ so,
                                                       unsigned short* __restrict__ z) {
    __shared__ float tile[16][264];
    __shared__ float mu_s[16], rs_s[16];
    const int c = threadIdx.x, chunk = blockIdx.x, b = blockIdx.y;
    const int wave = c >> 6, lane = c & 63;
    const float w = decay[c] * (1.0f / T_);
    const float u = first[c] * (1.0f / T_);
    const float gw = lw[c], gb = lb[c];
    size_t sidx = ((size_t)b * NC_ + chunk) * C_ + c;
    float p = sp[sidx], q = sq[sidx], o = so[sidx];
    size_t base = ((size_t)b * T_ + (size_t)chunk * L_) * C_ + c;

    for (int t = 0; t < L_; t += 8) {
        float kk[8], vv[8];
#pragma unroll
        for (int j = 0; j < 8; ++j) {
            kk[j] = b2f(k[base + (size_t)(t + j) * C_]);
            vv[j] = b2f(v[base + (size_t)(t + j) * C_]);
        }
#pragma unroll
        for (int j = 0; j < 8; ++j) {
            float uk = u + kk[j];
            float no = fmaxf(o, uk);
            float a = __expf(o - no), bb = __expf(uk - no);
            tile[t + j][c] = (a * p + bb * vv[j]) / (a * q + bb);
            float wo = w + o;
            float no2 = fmaxf(wo, kk[j]);
            float a2 = __expf(wo - no2), b2 = __expf(kk[j] - no2);
            p = a2 * p + b2 * vv[j];
            q = a2 * q + b2;
            o = no2;
        }
    }
    __syncthreads();
#pragma unroll
    for (int r = 0; r < 4; ++r) {
        const int j = wave * 4 + r;
        float4 t4 = *(const float4*)&tile[j][lane * 4];
        float s = t4.x + t4.y + t4.z + t4.w;
        float ss = t4.x * t4.x + t4.y * t4.y + t4.z * t4.z + t4.w * t4.w;
#pragma unroll
        for (int m = 1; m < 64; m <<= 1) {
            s += __shfl_xor(s, m, 64);
            ss += __shfl_xor(ss, m, 64);
        }
        if (lane == 0) {
            float mu = s * (1.f / C_);
            mu_s[j] = mu;
            rs_s[j] = rsqrtf(ss * (1.f / C_) - mu * mu + 1e-5f);
        }
    }
    __syncthreads();
#pragma unroll
    for (int j = 0; j < L_; ++j) {
        float zz = (tile[j][c] - mu_s[j]) * rs_s[j] * gw + gb;
        zz *= b2f(sr[base + (size_t)j * C_]);
        z[base + (size_t)j * C_] = f2b(zz);
    }
}

extern "C" void kernel_launch(void* const* d_in, const int* in_sizes, int n_in,
                              void* d_out, int out_size, void* d_ws, size_t ws_size,
                              hipStream_t stream) {
    const float* x     = (const float*)d_in[0];
    const float* Wk    = (const float*)d_in[1];
    const float* Wv    = (const float*)d_in[2];
    const float* Wr    = (const float*)d_in[3];
    const float* Wo    = (const float*)d_in[4];
    const float* decay = (const float*)d_in[5];
    const float* first = (const float*)d_in[6];
    const float* lnw   = (const float*)d_in[7];
    const float* lnb   = (const float*)d_in[8];
    float* out = (float*)d_out;

    char* ws = (char*)d_ws;
    const size_t NE = (size_t)M_ * C_;              // 8388608
    unsigned short* wb  = (unsigned short*)ws; ws += 4 * 65536 * 2;  // wk|wv|wr|wo
    unsigned short* kbuf = (unsigned short*)ws; ws += NE * 2;        // bf16 k
    unsigned short* vbuf = (unsigned short*)ws; ws += NE * 2;        // bf16 v
    unsigned short* srb = (unsigned short*)ws; ws += NE * 2;
    unsigned short* zb  = (unsigned short*)ws; ws += NE * 2;
    const size_t SE = (size_t)B_ * NC_ * C_;        // 524288
    float* sp = (float*)ws; ws += SE * 4;
    float* sq = (float*)ws; ws += SE * 4;
    float* so = (float*)ws; ws += SE * 4;
    unsigned short* wkb = wb;
    unsigned short* wvb = wb + 65536;
    unsigned short* wrb = wb + 2 * 65536;
    unsigned short* wob = wb + 3 * 65536;

    cvt_w<<<128, 256, 0, stream>>>(Wk, Wv, Wr, Wo, wb);

    // QKV + fused pass1: 512 row-blocks; 4 n-strips x 3 mats looped inside.
    // x read directly as f32 (exactly once device-wide), converted in-register.
    gemm_qkv<<<dim3(M_ / 64), 256, 0, stream>>>(x, wkb, wvb, wrb, decay,
                                                kbuf, vbuf, srb, sp, sq, so);

    wkv_combine_par<<<dim3(B_, C_ / 16), 256, 0, stream>>>(decay, sp, sq, so);
    wkv_pass2_ln<<<dim3(NC_, B_), 256, 0, stream>>>(kbuf, vbuf, srb, decay, first,
                                                    lnw, lnb, sp, sq, so, zb);

    // Output GEMM: 512 row-blocks, 4 n-strips looped inside
    gemm_out<<<dim3(M_ / 64), 256, 0, stream>>>(zb, wob, out);
}

// Round 20
// 156.974 us; speedup vs baseline: 1.6530x; 1.0047x over previous
//
#include <hip/hip_runtime.h>
#include <cstdint>
#include <cstddef>

#define B_ 8
#define T_ 4096
#define C_ 256
#define NC_ 256
#define L_ (T_ / NC_)   // 16 steps per chunk
#define M_ (B_ * T_)    // 32768 rows

typedef float f32x4 __attribute__((ext_vector_type(4)));
typedef short bf16x8 __attribute__((ext_vector_type(8)));

__device__ __forceinline__ unsigned short f2b(float f) {
    unsigned int u = __float_as_uint(f);
    u += 0x7fffu + ((u >> 16) & 1u);   // round-to-nearest-even
    return (unsigned short)(u >> 16);
}
__device__ __forceinline__ float b2f(unsigned short h) {
    return __uint_as_float(((unsigned int)h) << 16);
}

// ---------------- f32->bf16 convert: WEIGHTS ONLY (x fused into gemm_qkv) -----
__global__ __launch_bounds__(256) void cvt_w(const float* __restrict__ Wk,
                                             const float* __restrict__ Wv,
                                             const float* __restrict__ Wr,
                                             const float* __restrict__ Wo,
                                             unsigned short* __restrict__ wb) {
    const int r = blockIdx.x;              // 0..127
    const int mat = r >> 5;                // 0..3
    const float* src = (mat == 0) ? Wk : (mat == 1) ? Wv : (mat == 2) ? Wr : Wo;
    unsigned short* dst = wb + (size_t)mat * 65536;
    const size_t i = (size_t)(r & 31) * 2048 + (size_t)threadIdx.x * 8;
    float4 a = *(const float4*)(src + i);
    float4 b = *(const float4*)(src + i + 4);
    bf16x8 o;
    o[0] = (short)f2b(a.x); o[1] = (short)f2b(a.y);
    o[2] = (short)f2b(a.z); o[3] = (short)f2b(a.w);
    o[4] = (short)f2b(b.x); o[5] = (short)f2b(b.y);
    o[6] = (short)f2b(b.z); o[7] = (short)f2b(b.w);
    *(bf16x8*)(dst + i) = o;
}

// ---------------- QKV GEMM v14: DOUBLE-BUFFERED wlds, 1 barrier/phase ---------
// O[m,n] = sum_k A[m,k]*W[n,k], A = bf16(x) in-register. Grid (M/64) = 512
// blocks (2/CU), 4 strips x 3 mats = 12 phases. NEW (R20): wlds[2] double
// buffer -- phase p MFMAs read buf[p&1] while next W tile is written to the
// OTHER buffer; ONE __syncthreads per phase (was 2; hipcc drains vmcnt(0) at
// each). Disjoint buffers -> no R11-style aliasing hazard; deterministic.
// Stage is bf16 holding ALREADY-ROUNDED outputs (f2b/sigmoid applied to f32
// acc before staging) -> all rounding points bit-identical to R14, and LDS
// fits 2/CU: 2*33792 + 4*2304 = 76800 B. k/v/sr row-major bf16 (R13/R14).
__global__ __launch_bounds__(256, 3) void gemm_qkv(const float* __restrict__ x,
                                                   const unsigned short* __restrict__ w0,
                                                   const unsigned short* __restrict__ w1,
                                                   const unsigned short* __restrict__ w2,
                                                   const float* __restrict__ decay,
                                                   unsigned short* __restrict__ kb,
                                                   unsigned short* __restrict__ vb,
                                                   unsigned short* __restrict__ b2,
                                                   float* __restrict__ sp,
                                                   float* __restrict__ sq,
                                                   float* __restrict__ so) {
    __shared__ unsigned short wlds[2][64 * 264];   // 67584 B
    __shared__ unsigned short stg[4][16 * 72];     // 9216 B (bf16 stage, per-wave)
    const int tid = threadIdx.x;
    const int wave = tid >> 6, lane = tid & 63;
    const int quad = lane >> 4, l16 = lane & 15;
    const int m0 = blockIdx.x * 64 + wave * 16;
    unsigned short* myst = stg[wave];

    // A fragments from f32 x, converted in-register (bit-identical to cvt path)
    bf16x8 af[8];
    {
        const float* Ar = x + (size_t)(m0 + l16) * C_ + quad * 8;
#pragma unroll
        for (int kc = 0; kc < 8; ++kc) {
            float4 a = *(const float4*)(Ar + kc * 32);
            float4 b = *(const float4*)(Ar + kc * 32 + 4);
            bf16x8 o;
            o[0] = (short)f2b(a.x); o[1] = (short)f2b(a.y);
            o[2] = (short)f2b(a.z); o[3] = (short)f2b(a.w);
            o[4] = (short)f2b(b.x); o[5] = (short)f2b(b.y);
            o[6] = (short)f2b(b.z); o[7] = (short)f2b(b.w);
            af[kc] = o;
        }
    }

    const int r = tid >> 5;              // 0..7
    const int cs = (tid & 31) * 8;       // short offset, 16 B per lane

    // prologue: stage phase-0 W tile into wlds[0]
    bf16x8 tmp[8];
#pragma unroll
    for (int it = 0; it < 8; ++it)
        tmp[it] = *(const bf16x8*)(w0 + (size_t)(it * 8 + r) * C_ + cs);
    unsigned short* wrd = wlds[0];       // read buffer (this phase)
    unsigned short* wwr = wlds[1];       // write buffer (next phase)
#pragma unroll
    for (int it = 0; it < 8; ++it)
        *(bf16x8*)(wrd + (it * 8 + r) * 264 + cs) = tmp[it];
    __syncthreads();

    float kreg[16], vreg[16];            // chunk-local k/v (bf16-rounded)

    for (int s = 0; s < 4; ++s) {
        const int n0 = s * 64;
        for (int mat = 0; mat < 3; ++mat) {
            const bool last = (s == 3 && mat == 2);
            if (!last) {                 // prefetch next phase's W tile into regs
                const unsigned short* Wn = (mat == 0) ? w1 : (mat == 1) ? w2 : w0;
                const int nn = (mat == 2) ? n0 + 64 : n0;
#pragma unroll
                for (int it = 0; it < 8; ++it)
                    tmp[it] = *(const bf16x8*)(Wn + (size_t)(nn + it * 8 + r) * C_ + cs);
            }

            f32x4 acc[4];
#pragma unroll
            for (int nt = 0; nt < 4; ++nt) acc[nt] = (f32x4){0.f, 0.f, 0.f, 0.f};
#pragma unroll
            for (int nt = 0; nt < 4; ++nt) {
                const unsigned short* wrow = wrd + (nt * 16 + l16) * 264 + quad * 8;
#pragma unroll
                for (int kc = 0; kc < 8; ++kc) {
                    bf16x8 wf = *(const bf16x8*)(wrow + kc * 32);
                    acc[nt] = __builtin_amdgcn_mfma_f32_16x16x32_bf16(af[kc], wf, acc[nt], 0, 0, 0);
                }
            }

            // epilogue: round f32 acc -> bf16 stage (rounding identical to R14)
            if (mat == 2) {
#pragma unroll
                for (int nt = 0; nt < 4; ++nt)
#pragma unroll
                    for (int i = 0; i < 4; ++i)
                        myst[(quad * 4 + i) * 72 + nt * 16 + l16] =
                            f2b(1.f / (1.f + __expf(-acc[nt][i])));
            } else {
#pragma unroll
                for (int nt = 0; nt < 4; ++nt)
#pragma unroll
                    for (int i = 0; i < 4; ++i)
                        myst[(quad * 4 + i) * 72 + nt * 16 + l16] = f2b(acc[nt][i]);
            }
            // row-major global store (full-line ushort4, same pattern as R14)
            unsigned short* dstb = (mat == 0) ? kb : (mat == 1) ? vb : b2;
#pragma unroll
            for (int rr = 0; rr < 4; ++rr) {
                const int row = rr * 4 + quad;
                ushort4 t4 = *(const ushort4*)&myst[row * 72 + l16 * 4];
                *(ushort4*)(dstb + (size_t)(m0 + row) * C_ + n0 + l16 * 4) = t4;
            }

            // fused pass1: per-wave column snapshot; scan at mat==1
            if (mat == 0) {
#pragma unroll
                for (int j = 0; j < L_; ++j) kreg[j] = b2f(myst[j * 72 + lane]);
            } else if (mat == 1) {
#pragma unroll
                for (int j = 0; j < L_; ++j) vreg[j] = b2f(myst[j * 72 + lane]);
                const int ch = n0 + lane;
                const float w = decay[ch] * (1.0f / T_);
                float p = 0.f, q = 0.f, o = -1e38f;
#pragma unroll
                for (int j = 0; j < L_; ++j) {
                    float wo = w + o;
                    float no = fmaxf(wo, kreg[j]);
                    float a2 = __expf(wo - no), b2s = __expf(kreg[j] - no);
                    p = a2 * p + b2s * vreg[j];
                    q = a2 * q + b2s;
                    o = no;
                }
                const int bb = m0 / T_;
                const int chunk = (m0 % T_) / L_;
                const size_t idx = ((size_t)bb * NC_ + chunk) * C_ + ch;
                sp[idx] = p; sq[idx] = q; so[idx] = o;
            }

            if (!last) {
                // write NEXT phase's tile to the other buffer, swap, ONE barrier
#pragma unroll
                for (int it = 0; it < 8; ++it)
                    *(bf16x8*)(wwr + (it * 8 + r) * 264 + cs) = tmp[it];
                unsigned short* t = wrd; wrd = wwr; wwr = t;
                __syncthreads();
            }
        }
    }
}

// ---------------- output GEMM (R14 known-good): 4 n-strips looped -------------
__global__ __launch_bounds__(256, 3) void gemm_out(const unsigned short* __restrict__ A,
                                                   const unsigned short* __restrict__ w0,
                                                   float* __restrict__ f0) {
    __shared__ unsigned short wlds[64 * 264];   // 33792 B
    __shared__ float stage[4][16 * 68];         // 17408 B
    const int tid = threadIdx.x;
    const int wave = tid >> 6, lane = tid & 63;
    const int quad = lane >> 4, l16 = lane & 15;
    const int m0 = blockIdx.x * 64 + wave * 16;
    float* myst = stage[wave];

    bf16x8 af[8];
    {
        const unsigned short* Ar = A + (size_t)(m0 + l16) * C_ + quad * 8;
#pragma unroll
        for (int kc = 0; kc < 8; ++kc) af[kc] = *(const bf16x8*)(Ar + kc * 32);
    }

    const int r = tid >> 5;              // 0..7
    const int cs = (tid & 31) * 8;       // short offset, 16 B per lane

    bf16x8 tmp[8];
#pragma unroll
    for (int it = 0; it < 8; ++it)
        tmp[it] = *(const bf16x8*)(w0 + (size_t)(it * 8 + r) * C_ + cs);

    for (int s = 0; s < 4; ++s) {
        const int n0 = s * 64;
        __syncthreads();                 // prev strip's wlds reads done
#pragma unroll
        for (int it = 0; it < 8; ++it)
            *(bf16x8*)(wlds + (it * 8 + r) * 264 + cs) = tmp[it];
        __syncthreads();                 // wlds visible to all waves

        if (s < 3) {                     // prefetch next strip's W rows
#pragma unroll
            for (int it = 0; it < 8; ++it)
                tmp[it] = *(const bf16x8*)(w0 + (size_t)(n0 + 64 + it * 8 + r) * C_ + cs);
        }

        f32x4 acc[4];
#pragma unroll
        for (int nt = 0; nt < 4; ++nt) acc[nt] = (f32x4){0.f, 0.f, 0.f, 0.f};
#pragma unroll
        for (int nt = 0; nt < 4; ++nt) {
            const unsigned short* wrow = wlds + (nt * 16 + l16) * 264 + quad * 8;
#pragma unroll
            for (int kc = 0; kc < 8; ++kc) {
                bf16x8 wf = *(const bf16x8*)(wrow + kc * 32);
                acc[nt] = __builtin_amdgcn_mfma_f32_16x16x32_bf16(af[kc], wf, acc[nt], 0, 0, 0);
            }
        }

#pragma unroll
        for (int nt = 0; nt < 4; ++nt)
#pragma unroll
            for (int i = 0; i < 4; ++i)
                myst[(quad * 4 + i) * 68 + nt * 16 + l16] = acc[nt][i];
#pragma unroll
        for (int rr = 0; rr < 4; ++rr) {
            const int row = rr * 4 + quad;
            float4 t4 = *(const float4*)&myst[row * 68 + l16 * 4];
            *(float4*)(f0 + (size_t)(m0 + row) * C_ + n0 + l16 * 4) = t4;
        }
    }
}

// ---------------- WKV combine: PARALLEL segmented scan over chunks ------------
__global__ __launch_bounds__(256) void wkv_combine_par(const float* __restrict__ decay,
                                                       float* __restrict__ sp,
                                                       float* __restrict__ sq,
                                                       float* __restrict__ so) {
    __shared__ float tp[16][17], tq[16][17], to[16][17];
    const int tid = threadIdx.x;
    const int cgi = tid >> 4;
    const int cl = tid & 15;
    const int b = blockIdx.x;
    const int c = blockIdx.y * 16 + cl;
    const float wL = decay[c] * (1.0f / T_) * (float)L_;
    const float wL16 = wL * 16.0f;
    const size_t base = ((size_t)b * NC_ + (size_t)cgi * 16) * C_ + c;

    float p = 0.f, q = 0.f, o = -1e38f;
#pragma unroll 4
    for (int j = 0; j < 16; ++j) {
        size_t idx = base + (size_t)j * C_;
        float lp = sp[idx], lq = sq[idx], lo = so[idx];
        float ow = o + wL;
        float no = fmaxf(ow, lo);
        float ea = __expf(ow - no), eb = __expf(lo - no);
        p = ea * p + eb * lp;
        q = ea * q + eb * lq;
        o = no;
    }
    tp[cgi][cl] = p; tq[cgi][cl] = q; to[cgi][cl] = o;

    float ip = p, iq = q, io = o;
#pragma unroll
    for (int off = 1; off < 16; off <<= 1) {
        __syncthreads();
        float ap = 0.f, aq = 0.f, ao = 0.f;
        const bool doit = (cgi >= off);
        if (doit) { ap = tp[cgi - off][cl]; aq = tq[cgi - off][cl]; ao = to[cgi - off][cl]; }
        __syncthreads();
        if (doit) {
            float ow = ao + (float)off * wL16;
            float no = fmaxf(ow, io);
            float ea = __expf(ow - no), eb = __expf(io - no);
            ip = ea * ap + eb * ip;
            iq = ea * aq + eb * iq;
            io = no;
            tp[cgi][cl] = ip; tq[cgi][cl] = iq; to[cgi][cl] = io;
        }
    }
    __syncthreads();

    float ep, eq, eo;
    if (cgi == 0) { ep = 0.f; eq = 0.f; eo = -1e38f; }
    else          { ep = tp[cgi - 1][cl]; eq = tq[cgi - 1][cl]; eo = to[cgi - 1][cl]; }

    for (int j = 0; j < 16; ++j) {
        size_t idx = base + (size_t)j * C_;
        float lp = sp[idx], lq = sq[idx], lo = so[idx];
        sp[idx] = ep; sq[idx] = eq; so[idx] = eo;
        float ow = eo + wL;
        float no = fmaxf(ow, lo);
        float ea = __expf(ow - no), eb = __expf(lo - no);
        ep = ea * ep + eb * lp;
        eq = ea * eq + eb * lq;
        eo = no;
    }
}

// ---------------- WKV pass 2 + LayerNorm + gate (bf16 k/v inputs) --------------
__global__ __launch_bounds__(256, 8) void wkv_pass2_ln(const unsigned short* __restrict__ k,
                                                       const unsigned short* __restrict__ v,
                                                       const unsigned short* __restrict__ sr,
                                                       const float* __restrict__ decay,
                                                       const float* __restrict__ first,
                                                       const float* __restrict__ lw,
                                                       const float* __restrict__ lb,
                                                       const float* __restrict__ sp,
                                                       const float* __restrict__ sq,
                                                       const float* __restrict__ so,
                                                       unsigned short* __restrict__ z) {
    __shared__ float tile[16][264];
    __shared__ float mu_s[16], rs_s[16];
    const int c = threadIdx.x, chunk = blockIdx.x, b = blockIdx.y;
    const int wave = c >> 6, lane = c & 63;
    const float w = decay[c] * (1.0f / T_);
    const float u = first[c] * (1.0f / T_);
    const float gw = lw[c], gb = lb[c];
    size_t sidx = ((size_t)b * NC_ + chunk) * C_ + c;
    float p = sp[sidx], q = sq[sidx], o = so[sidx];
    size_t base = ((size_t)b * T_ + (size_t)chunk * L_) * C_ + c;

    for (int t = 0; t < L_; t += 8) {
        float kk[8], vv[8];
#pragma unroll
        for (int j = 0; j < 8; ++j) {
            kk[j] = b2f(k[base + (size_t)(t + j) * C_]);
            vv[j] = b2f(v[base + (size_t)(t + j) * C_]);
        }
#pragma unroll
        for (int j = 0; j < 8; ++j) {
            float uk = u + kk[j];
            float no = fmaxf(o, uk);
            float a = __expf(o - no), bb = __expf(uk - no);
            tile[t + j][c] = (a * p + bb * vv[j]) / (a * q + bb);
            float wo = w + o;
            float no2 = fmaxf(wo, kk[j]);
            float a2 = __expf(wo - no2), b2 = __expf(kk[j] - no2);
            p = a2 * p + b2 * vv[j];
            q = a2 * q + b2;
            o = no2;
        }
    }
    __syncthreads();
#pragma unroll
    for (int r = 0; r < 4; ++r) {
        const int j = wave * 4 + r;
        float4 t4 = *(const float4*)&tile[j][lane * 4];
        float s = t4.x + t4.y + t4.z + t4.w;
        float ss = t4.x * t4.x + t4.y * t4.y + t4.z * t4.z + t4.w * t4.w;
#pragma unroll
        for (int m = 1; m < 64; m <<= 1) {
            s += __shfl_xor(s, m, 64);
            ss += __shfl_xor(ss, m, 64);
        }
        if (lane == 0) {
            float mu = s * (1.f / C_);
            mu_s[j] = mu;
            rs_s[j] = rsqrtf(ss * (1.f / C_) - mu * mu + 1e-5f);
        }
    }
    __syncthreads();
#pragma unroll
    for (int j = 0; j < L_; ++j) {
        float zz = (tile[j][c] - mu_s[j]) * rs_s[j] * gw + gb;
        zz *= b2f(sr[base + (size_t)j * C_]);
        z[base + (size_t)j * C_] = f2b(zz);
    }
}

extern "C" void kernel_launch(void* const* d_in, const int* in_sizes, int n_in,
                              void* d_out, int out_size, void* d_ws, size_t ws_size,
                              hipStream_t stream) {
    const float* x     = (const float*)d_in[0];
    const float* Wk    = (const float*)d_in[1];
    const float* Wv    = (const float*)d_in[2];
    const float* Wr    = (const float*)d_in[3];
    const float* Wo    = (const float*)d_in[4];
    const float* decay = (const float*)d_in[5];
    const float* first = (const float*)d_in[6];
    const float* lnw   = (const float*)d_in[7];
    const float* lnb   = (const float*)d_in[8];
    float* out = (float*)d_out;

    char* ws = (char*)d_ws;
    const size_t NE = (size_t)M_ * C_;              // 8388608
    unsigned short* wb  = (unsigned short*)ws; ws += 4 * 65536 * 2;  // wk|wv|wr|wo
    unsigned short* kbuf = (unsigned short*)ws; ws += NE * 2;        // bf16 k
    unsigned short* vbuf = (unsigned short*)ws; ws += NE * 2;        // bf16 v
    unsigned short* srb = (unsigned short*)ws; ws += NE * 2;
    unsigned short* zb  = (unsigned short*)ws; ws += NE * 2;
    const size_t SE = (size_t)B_ * NC_ * C_;        // 524288
    float* sp = (float*)ws; ws += SE * 4;
    float* sq = (float*)ws; ws += SE * 4;
    float* so = (float*)ws; ws += SE * 4;
    unsigned short* wkb = wb;
    unsigned short* wvb = wb + 65536;
    unsigned short* wrb = wb + 2 * 65536;
    unsigned short* wob = wb + 3 * 65536;

    cvt_w<<<128, 256, 0, stream>>>(Wk, Wv, Wr, Wo, wb);

    // QKV + fused pass1: 512 row-blocks; 4 n-strips x 3 mats looped inside,
    // double-buffered W tiles (1 barrier/phase).
    gemm_qkv<<<dim3(M_ / 64), 256, 0, stream>>>(x, wkb, wvb, wrb, decay,
                                                kbuf, vbuf, srb, sp, sq, so);

    wkv_combine_par<<<dim3(B_, C_ / 16), 256, 0, stream>>>(decay, sp, sq, so);
    wkv_pass2_ln<<<dim3(NC_, B_), 256, 0, stream>>>(kbuf, vbuf, srb, decay, first,
                                                    lnw, lnb, sp, sq, so, zb);

    // Output GEMM: 512 row-blocks, 4 n-strips looped inside
    gemm_out<<<dim3(M_ / 64), 256, 0, stream>>>(zb, wob, out);
}